// Round 8
// baseline (49.226 us; speedup 1.0000x reference)
//
#include <hip/hip_runtime.h>

#define NPTS 8192
#define DIM  32
#define TILE 128
#define TPB  256
#define NT   (NPTS / TILE)          /* 64 tiles per dim */
#define NBLK (NT * (NT + 1) / 2)    /* 2080 upper-tri blocks */
#define ROWS 72                     /* shorts per LDS row: 32 hi | 32 lo | 8 pad (144B stride) */

typedef __attribute__((ext_vector_type(8))) short short8;   // 8 bf16 = 4 VGPR (MFMA A/B frag)
typedef __attribute__((ext_vector_type(4))) float floatx4;  // MFMA C/D frag

// codon index (dict order of CODON_TABLE) -> biosynthetic family id, -1 = stop.
__device__ const int FID[64] = {
    4,4,3,3, 3,3,3,3, 1,1,1,1, 3,3,3,3,   // UUx CUx AUx GUx
    2,2,2,2, 0,0,0,0, 1,1,1,1, 3,3,3,3,   // UCx CCx ACx GCx
    4,4,-1,-1, 5,5,0,0, 1,1,1,1, 1,1,0,0, // UAx CAx AAx GAx
    2,2,-1,4, 0,0,0,0, 2,2,0,0, 2,2,2,2   // UGx CGx AGx GGx
};

__device__ __forceinline__ unsigned short bf16_rne(float f) {
    unsigned u = __float_as_uint(f);
    unsigned r = u + 0x7FFFu + ((u >> 16) & 1u);   // round-to-nearest-even
    return (unsigned short)(r >> 16);
}
__device__ __forceinline__ float bf16_f(unsigned short h) {
    return __uint_as_float(((unsigned)h) << 16);
}

// Per-point squared norm (exact f32) + family id. No histogram, no atomics —
// counts are recomputed from idx in reduce_kernel (removes the 39us memset).
__global__ void prep_kernel(const float* __restrict__ x, const int* __restrict__ idx,
                            float* __restrict__ sq, int* __restrict__ fid) {
    int gid = blockIdx.x * blockDim.x + threadIdx.x;
    const float4* p = (const float4*)(x + (size_t)gid * DIM);
    float s = 0.f;
#pragma unroll
    for (int v = 0; v < 8; ++v) {
        float4 f = p[v];
        s += f.x * f.x + f.y * f.y + f.z * f.z + f.w * f.w;
    }
    sq[gid] = s;
    int f = FID[idx[gid] & 63];
    fid[gid] = (f >= 0) ? f : (-10 - gid);   // unique negatives: equality never matches
}

// 128x128 pair tile per block via bf16 hi/lo-split MFMA (3 passes, exact to ~1e-5).
// 4 waves; wave w owns rows [w*32, w*32+32) x all 128 cols = 2x8 16x16 subtiles.
// Per-block partial-sum STORES (R6->R7: atomics were a 4160-way serialized
// cross-XCD RMW floor at ~66us).
__global__ __launch_bounds__(TPB, 2) void pair_kernel(const float* __restrict__ x,
                                                      const float* __restrict__ sq,
                                                      const int* __restrict__ fid,
                                                      double* __restrict__ partials) {
    __shared__ __align__(16) short Ash[TILE][ROWS];
    __shared__ __align__(16) short Bsh[TILE][ROWS];
    __shared__ double red[4][2];

    // linear block id -> upper-tri (I, J), J >= I
    int b = blockIdx.x;
    int I = (int)((2 * NT + 1 - sqrtf((float)((2 * NT + 1) * (2 * NT + 1) - 8 * b))) * 0.5f);
    if (I < 0) I = 0;
    if (I > NT - 1) I = NT - 1;
    while ((I + 1) * NT - (I + 1) * I / 2 <= b) ++I;
    while (I * NT - I * (I - 1) / 2 > b) --I;
    int J = I + (b - (I * NT - I * (I - 1) / 2));
    int I0 = I * TILE, J0 = J * TILE;

    int tid = threadIdx.x;
    {   // stage both tiles: f32 -> bf16 hi/lo into LDS. thread = (point, half).
        int pnt = tid >> 1, h = tid & 1;
        const floatx4* srcA = (const floatx4*)(x + (size_t)(I0 + pnt) * DIM + h * 16);
        const floatx4* srcB = (const floatx4*)(x + (size_t)(J0 + pnt) * DIM + h * 16);
        float f[16];
#pragma unroll
        for (int side = 0; side < 2; ++side) {
            const floatx4* src = side ? srcB : srcA;
            short* dst = side ? &Bsh[pnt][0] : &Ash[pnt][0];
            *(floatx4*)&f[0]  = src[0];
            *(floatx4*)&f[4]  = src[1];
            *(floatx4*)&f[8]  = src[2];
            *(floatx4*)&f[12] = src[3];
            short8 hi0, hi1, lo0, lo1;
#pragma unroll
            for (int i = 0; i < 8; ++i) {
                unsigned short hb = bf16_rne(f[i]);
                unsigned short lb = bf16_rne(f[i] - bf16_f(hb));
                hi0[i] = (short)hb; lo0[i] = (short)lb;
            }
#pragma unroll
            for (int i = 0; i < 8; ++i) {
                unsigned short hb = bf16_rne(f[8 + i]);
                unsigned short lb = bf16_rne(f[8 + i] - bf16_f(hb));
                hi1[i] = (short)hb; lo1[i] = (short)lb;
            }
            *(short8*)&dst[h * 16]          = hi0;
            *(short8*)&dst[h * 16 + 8]      = hi1;
            *(short8*)&dst[32 + h * 16]     = lo0;
            *(short8*)&dst[32 + h * 16 + 8] = lo1;
        }
    }
    __syncthreads();

    int lane = tid & 63, w = tid >> 6;
    int r16 = lane & 15, kg = lane >> 4;   // M/N index, k-group

    // A fragments (held): 2 row-subtiles x {hi,lo}
    short8 ah[2], al[2];
#pragma unroll
    for (int i = 0; i < 2; ++i) {
        int row = w * 32 + i * 16 + r16;
        ah[i] = *(const short8*)&Ash[row][kg * 8];
        al[i] = *(const short8*)&Ash[row][32 + kg * 8];
    }

    floatx4 acc[2][8];
#pragma unroll
    for (int i = 0; i < 2; ++i)
#pragma unroll
        for (int j = 0; j < 8; ++j) acc[i][j] = (floatx4)(0.f);

#pragma unroll
    for (int j = 0; j < 8; ++j) {
        int rowb = j * 16 + r16;
        short8 bh = *(const short8*)&Bsh[rowb][kg * 8];
        short8 bl = *(const short8*)&Bsh[rowb][32 + kg * 8];
#pragma unroll
        for (int i = 0; i < 2; ++i) {
            acc[i][j] = __builtin_amdgcn_mfma_f32_16x16x32_bf16(ah[i], bh, acc[i][j], 0, 0, 0);
            acc[i][j] = __builtin_amdgcn_mfma_f32_16x16x32_bf16(ah[i], bl, acc[i][j], 0, 0, 0);
            acc[i][j] = __builtin_amdgcn_mfma_f32_16x16x32_bf16(al[i], bh, acc[i][j], 0, 0, 0);
        }
    }

    // Epilogue. C/D layout (HW-verified): col = lane&15, row = (lane>>4)*4 + reg.
    float sqa[2][4]; int fa[2][4];
#pragma unroll
    for (int i = 0; i < 2; ++i)
#pragma unroll
        for (int r = 0; r < 4; ++r) {
            int row = I0 + w * 32 + i * 16 + kg * 4 + r;
            sqa[i][r] = sq[row]; fa[i][r] = fid[row];
        }
    float sqb[8]; int fb[8];
#pragma unroll
    for (int j = 0; j < 8; ++j) {
        int col = J0 + j * 16 + r16;
        sqb[j] = sq[col]; fb[j] = fid[col];
    }

    bool diagblk = (I == J);
    float s_all = 0.f, s_same = 0.f;
#pragma unroll
    for (int j = 0; j < 8; ++j) {
#pragma unroll
        for (int i = 0; i < 2; ++i) {
#pragma unroll
            for (int r = 0; r < 4; ++r) {
                float sqd = sqa[i][r] + sqb[j] - 2.f * acc[i][j][r];
                float dst = sqrtf(fmaxf(sqd, 0.f));
                if (diagblk) {
                    int lrow = w * 32 + i * 16 + kg * 4 + r;
                    int lcol = j * 16 + r16;
                    if (lrow >= lcol) dst = 0.f;   // strict upper triangle on diag blocks
                }
                s_all += dst;
                s_same += (fa[i][r] == fb[j]) ? dst : 0.f;
            }
        }
    }
    s_all *= 2.f;   // symmetry weight
    s_same *= 2.f;

#pragma unroll
    for (int off = 32; off >= 1; off >>= 1) {
        s_all  += __shfl_xor(s_all, off);
        s_same += __shfl_xor(s_same, off);
    }
    if ((tid & 63) == 0) { red[w][0] = (double)s_all; red[w][1] = (double)s_same; }
    __syncthreads();
    if (tid == 0) {
        partials[2 * b]     = red[0][0] + red[1][0] + red[2][0] + red[3][0];
        partials[2 * b + 1] = red[0][1] + red[1][1] + red[2][1] + red[3][1];
    }
}

// One block: family histogram from idx (LDS, block-local — no global init
// needed) + fixed-order tree reduce of 2080x2 doubles + final loss.
__global__ void reduce_kernel(const double* __restrict__ partials,
                              const int* __restrict__ idx,
                              float* __restrict__ out) {
    __shared__ double sh[4][2];
    __shared__ int hist[8];
    int tid = threadIdx.x;
    if (tid < 8) hist[tid] = 0;
    __syncthreads();
    for (int i = tid; i < NPTS; i += TPB) {
        int f = FID[idx[i] & 63];
        if (f >= 0) atomicAdd(&hist[f], 1);
    }

    double ta = 0.0, ts = 0.0;
    for (int i = tid; i < NBLK; i += TPB) {
        ta += partials[2 * i];
        ts += partials[2 * i + 1];
    }
#pragma unroll
    for (int off = 32; off >= 1; off >>= 1) {
        ta += __shfl_xor(ta, off);
        ts += __shfl_xor(ts, off);
    }
    if ((tid & 63) == 0) { sh[tid >> 6][0] = ta; sh[tid >> 6][1] = ts; }
    __syncthreads();
    if (tid == 0) {
        double s_all  = sh[0][0] + sh[1][0] + sh[2][0] + sh[3][0];
        double s_same = sh[0][1] + sh[1][1] + sh[2][1] + sh[3][1];
        double csame = 0.0;
#pragma unroll
        for (int f = 0; f < 6; ++f) csame += (double)hist[f] * (double)hist[f];
        double cdiff = (double)NPTS * (double)NPTS - csame;
        double same_mean = s_same / (csame + 1e-10);
        double diff_mean = (s_all - s_same) / (cdiff + 1e-10);
        double loss = same_mean - 0.5 * diff_mean + 1.0;
        out[0] = (float)(loss > 0.0 ? loss : 0.0);
    }
}

extern "C" void kernel_launch(void* const* d_in, const int* in_sizes, int n_in,
                              void* d_out, int out_size, void* d_ws, size_t ws_size,
                              hipStream_t stream) {
    const float* x  = (const float*)d_in[0];   // (16,512,32) f32 -> 8192x32
    const int* idx  = (const int*)d_in[1];     // (16,512) int
    float* out      = (float*)d_out;

    // ws layout: [0..64) unused; [64..33344) double partials[2*NBLK];
    //            [33344..66112) f32 sq[8192]; [66112..98880) i32 fid[8192]
    double* partials = (double*)((char*)d_ws + 64);
    float* sq        = (float*)((char*)d_ws + 64 + NBLK * 2 * sizeof(double));
    int* fid         = (int*)((char*)d_ws + 64 + NBLK * 2 * sizeof(double) + NPTS * sizeof(float));

    prep_kernel<<<NPTS / TPB, TPB, 0, stream>>>(x, idx, sq, fid);
    pair_kernel<<<NBLK, TPB, 0, stream>>>(x, sq, fid, partials);
    reduce_kernel<<<1, TPB, 0, stream>>>(partials, idx, out);
}

// Round 9
// 45.589 us; speedup vs baseline: 1.0798x; 1.0798x over previous
//
#include <hip/hip_runtime.h>

#define NPTS 8192
#define DIM  32
#define TILE 128
#define TPB  256
#define NT   (NPTS / TILE)          /* 64 tiles per dim */
#define NBLK (NT * (NT + 1) / 2)    /* 2080 upper-tri blocks */
#define ROWS 72                     /* shorts per LDS row: 32 hi | 32 lo | 8 pad (144B stride) */

typedef __attribute__((ext_vector_type(8))) short short8;   // 8 bf16 = 4 VGPR (MFMA A/B frag)
typedef __attribute__((ext_vector_type(4))) float floatx4;  // MFMA C/D frag

// codon index (dict order of CODON_TABLE) -> biosynthetic family id, -1 = stop.
__device__ const int FID[64] = {
    4,4,3,3, 3,3,3,3, 1,1,1,1, 3,3,3,3,   // UUx CUx AUx GUx
    2,2,2,2, 0,0,0,0, 1,1,1,1, 3,3,3,3,   // UCx CCx ACx GCx
    4,4,-1,-1, 5,5,0,0, 1,1,1,1, 1,1,0,0, // UAx CAx AAx GAx
    2,2,-1,4, 0,0,0,0, 2,2,0,0, 2,2,2,2   // UGx CGx AGx GGx
};

__device__ __forceinline__ unsigned short bf16_rne(float f) {
    unsigned u = __float_as_uint(f);
    unsigned r = u + 0x7FFFu + ((u >> 16) & 1u);   // round-to-nearest-even
    return (unsigned short)(r >> 16);
}
__device__ __forceinline__ float bf16_f(unsigned short h) {
    return __uint_as_float(((unsigned)h) << 16);
}

// 128x128 pair tile per block via bf16 hi/lo-split MFMA (3 passes, ~1e-5 exact).
// prep is FUSED: sq + fid computed in-block during staging (no prep kernel, no
// sq/fid global round-trip). 4 blocks/CU for cross-block phase overlap.
__global__ __launch_bounds__(TPB, 4) void pair_kernel(const float* __restrict__ x,
                                                      const int* __restrict__ idx,
                                                      double* __restrict__ partials) {
    __shared__ __align__(16) short Ash[TILE][ROWS];
    __shared__ __align__(16) short Bsh[TILE][ROWS];
    __shared__ float sqA[TILE], sqB[TILE];
    __shared__ int   fA[TILE],  fB[TILE];
    __shared__ double red[4][2];

    // linear block id -> upper-tri (I, J), J >= I
    int b = blockIdx.x;
    int I = (int)((2 * NT + 1 - sqrtf((float)((2 * NT + 1) * (2 * NT + 1) - 8 * b))) * 0.5f);
    if (I < 0) I = 0;
    if (I > NT - 1) I = NT - 1;
    while ((I + 1) * NT - (I + 1) * I / 2 <= b) ++I;
    while (I * NT - I * (I - 1) / 2 > b) --I;
    int J = I + (b - (I * NT - I * (I - 1) / 2));
    int I0 = I * TILE, J0 = J * TILE;

    int tid = threadIdx.x;
    {   // stage both tiles: f32 -> bf16 hi/lo into LDS; fused sq. thread = (point, half).
        int pnt = tid >> 1, h = tid & 1;
        const floatx4* srcA = (const floatx4*)(x + (size_t)(I0 + pnt) * DIM + h * 16);
        const floatx4* srcB = (const floatx4*)(x + (size_t)(J0 + pnt) * DIM + h * 16);
        float f[16];
        float sa = 0.f, sb = 0.f;
#pragma unroll
        for (int side = 0; side < 2; ++side) {
            const floatx4* src = side ? srcB : srcA;
            short* dst = side ? &Bsh[pnt][0] : &Ash[pnt][0];
            *(floatx4*)&f[0]  = src[0];
            *(floatx4*)&f[4]  = src[1];
            *(floatx4*)&f[8]  = src[2];
            *(floatx4*)&f[12] = src[3];
            float s = 0.f;
#pragma unroll
            for (int i = 0; i < 16; ++i) s += f[i] * f[i];
            if (side) sb = s; else sa = s;
            short8 hi0, hi1, lo0, lo1;
#pragma unroll
            for (int i = 0; i < 8; ++i) {
                unsigned short hb = bf16_rne(f[i]);
                unsigned short lb = bf16_rne(f[i] - bf16_f(hb));
                hi0[i] = (short)hb; lo0[i] = (short)lb;
            }
#pragma unroll
            for (int i = 0; i < 8; ++i) {
                unsigned short hb = bf16_rne(f[8 + i]);
                unsigned short lb = bf16_rne(f[8 + i] - bf16_f(hb));
                hi1[i] = (short)hb; lo1[i] = (short)lb;
            }
            *(short8*)&dst[h * 16]          = hi0;
            *(short8*)&dst[h * 16 + 8]      = hi1;
            *(short8*)&dst[32 + h * 16]     = lo0;
            *(short8*)&dst[32 + h * 16 + 8] = lo1;
        }
        // combine the two halves of each point (lanes tid, tid^1 share a point)
        sa += __shfl_xor(sa, 1);
        sb += __shfl_xor(sb, 1);
        if (h == 0) {
            sqA[pnt] = sa; sqB[pnt] = sb;
            int fa_ = FID[idx[I0 + pnt] & 63];
            int fb_ = FID[idx[J0 + pnt] & 63];
            fA[pnt] = (fa_ >= 0) ? fa_ : -(10 + I0 + pnt);  // unique per global pos:
            fB[pnt] = (fb_ >= 0) ? fb_ : -(10 + J0 + pnt);  // stops never match (diag=0 anyway)
        }
    }
    __syncthreads();

    int lane = tid & 63, w = tid >> 6;
    int r16 = lane & 15, kg = lane >> 4;   // M/N index, k-group

    // A fragments (held): 2 row-subtiles x {hi,lo}
    short8 ah[2], al[2];
#pragma unroll
    for (int i = 0; i < 2; ++i) {
        int row = w * 32 + i * 16 + r16;
        ah[i] = *(const short8*)&Ash[row][kg * 8];
        al[i] = *(const short8*)&Ash[row][32 + kg * 8];
    }

    floatx4 acc[2][8];
#pragma unroll
    for (int i = 0; i < 2; ++i)
#pragma unroll
        for (int j = 0; j < 8; ++j) acc[i][j] = (floatx4)(0.f);

#pragma unroll
    for (int j = 0; j < 8; ++j) {
        int rowb = j * 16 + r16;
        short8 bh = *(const short8*)&Bsh[rowb][kg * 8];
        short8 bl = *(const short8*)&Bsh[rowb][32 + kg * 8];
#pragma unroll
        for (int i = 0; i < 2; ++i) {
            acc[i][j] = __builtin_amdgcn_mfma_f32_16x16x32_bf16(ah[i], bh, acc[i][j], 0, 0, 0);
            acc[i][j] = __builtin_amdgcn_mfma_f32_16x16x32_bf16(ah[i], bl, acc[i][j], 0, 0, 0);
            acc[i][j] = __builtin_amdgcn_mfma_f32_16x16x32_bf16(al[i], bh, acc[i][j], 0, 0, 0);
        }
    }

    // Epilogue. C/D layout (HW-verified): col = lane&15, row = (lane>>4)*4 + reg.
    float sqa[2][4]; int fa[2][4];
#pragma unroll
    for (int i = 0; i < 2; ++i)
#pragma unroll
        for (int r = 0; r < 4; ++r) {
            int row = w * 32 + i * 16 + kg * 4 + r;
            sqa[i][r] = sqA[row]; fa[i][r] = fA[row];
        }
    float sqb[8]; int fb[8];
#pragma unroll
    for (int j = 0; j < 8; ++j) {
        int col = j * 16 + r16;
        sqb[j] = sqB[col]; fb[j] = fB[col];
    }

    bool diagblk = (I == J);
    float s_all = 0.f, s_same = 0.f;
#pragma unroll
    for (int j = 0; j < 8; ++j) {
#pragma unroll
        for (int i = 0; i < 2; ++i) {
#pragma unroll
            for (int r = 0; r < 4; ++r) {
                float sqd = sqa[i][r] + sqb[j] - 2.f * acc[i][j][r];
                float dst = sqrtf(fmaxf(sqd, 0.f));
                if (diagblk) {
                    int lrow = w * 32 + i * 16 + kg * 4 + r;
                    int lcol = j * 16 + r16;
                    if (lrow >= lcol) dst = 0.f;   // strict upper triangle on diag blocks
                }
                s_all += dst;
                s_same += (fa[i][r] == fb[j]) ? dst : 0.f;
            }
        }
    }
    s_all *= 2.f;   // symmetry weight
    s_same *= 2.f;

#pragma unroll
    for (int off = 32; off >= 1; off >>= 1) {
        s_all  += __shfl_xor(s_all, off);
        s_same += __shfl_xor(s_same, off);
    }
    if ((tid & 63) == 0) { red[w][0] = (double)s_all; red[w][1] = (double)s_same; }
    __syncthreads();
    if (tid == 0) {
        partials[2 * b]     = red[0][0] + red[1][0] + red[2][0] + red[3][0];
        partials[2 * b + 1] = red[0][1] + red[1][1] + red[2][1] + red[3][1];
    }
}

// One block: family histogram from idx (LDS, block-local — no global init
// needed) + fixed-order tree reduce of 2080x2 doubles + final loss.
__global__ void reduce_kernel(const double* __restrict__ partials,
                              const int* __restrict__ idx,
                              float* __restrict__ out) {
    __shared__ double sh[4][2];
    __shared__ int hist[8];
    int tid = threadIdx.x;
    if (tid < 8) hist[tid] = 0;
    __syncthreads();
    for (int i = tid; i < NPTS; i += TPB) {
        int f = FID[idx[i] & 63];
        if (f >= 0) atomicAdd(&hist[f], 1);
    }

    double ta = 0.0, ts = 0.0;
    for (int i = tid; i < NBLK; i += TPB) {
        ta += partials[2 * i];
        ts += partials[2 * i + 1];
    }
#pragma unroll
    for (int off = 32; off >= 1; off >>= 1) {
        ta += __shfl_xor(ta, off);
        ts += __shfl_xor(ts, off);
    }
    if ((tid & 63) == 0) { sh[tid >> 6][0] = ta; sh[tid >> 6][1] = ts; }
    __syncthreads();
    if (tid == 0) {
        double s_all  = sh[0][0] + sh[1][0] + sh[2][0] + sh[3][0];
        double s_same = sh[0][1] + sh[1][1] + sh[2][1] + sh[3][1];
        double csame = 0.0;
#pragma unroll
        for (int f = 0; f < 6; ++f) csame += (double)hist[f] * (double)hist[f];
        double cdiff = (double)NPTS * (double)NPTS - csame;
        double same_mean = s_same / (csame + 1e-10);
        double diff_mean = (s_all - s_same) / (cdiff + 1e-10);
        double loss = same_mean - 0.5 * diff_mean + 1.0;
        out[0] = (float)(loss > 0.0 ? loss : 0.0);
    }
}

extern "C" void kernel_launch(void* const* d_in, const int* in_sizes, int n_in,
                              void* d_out, int out_size, void* d_ws, size_t ws_size,
                              hipStream_t stream) {
    const float* x  = (const float*)d_in[0];   // (16,512,32) f32 -> 8192x32
    const int* idx  = (const int*)d_in[1];     // (16,512) int
    float* out      = (float*)d_out;

    // ws layout: [0..33280) double partials[2*NBLK]
    double* partials = (double*)d_ws;

    pair_kernel<<<NBLK, TPB, 0, stream>>>(x, idx, partials);
    reduce_kernel<<<1, TPB, 0, stream>>>(partials, idx, out);
}